// Round 5
// baseline (1127.516 us; speedup 1.0000x reference)
//
#include <hip/hip_runtime.h>
#include <hip/hip_bf16.h>

// VectorQuantizer: z [8,64,64,64] fp32 (BCHW), embedding [8192,64] fp32.
// Outputs (concat): z_q [8,64,64,64] fp32 (BCHW), indices [32768] as fp32.
//
// argmin_n ||zn - e_n||^2 == argmin_n ( 0.5*||e_n||^2 - inv_p * (z_raw . e_n) )
// (||zn||^2 const per pixel; inv_p = 1/max(||z_p||,eps) > 0 factored out of the dot)
//
// R5 design notes (counter evidence):
//  - R2/R4: allocator refuses >56 VGPR for a 256-thr kernel regardless of
//    launch_bounds -> zr[64]-in-registers is unwinnable. This version needs
//    only ~40 VGPRs: 16 accumulators (16 codes in flight) + one z float4.
//  - z streams from LDS: 1 ds_read_b128 (12 cyc) feeds 64 FMAs (128 cyc),
//    vs R3's 16 reads/code (LDS-bound, 1180 us). LDS duty ~9%.
//  - e streams on the scalar pipe (s_load): R1/R2/R4 SGPR counts prove the
//    wave-uniform address scalarizes. Scalar pipe runs parallel to VALU.

#define NPIX 32768
#define NE   8192
#define EDIM 64
#define HW   4096            // 64*64
#define NGRP 16
#define CPT  (NE / NGRP)     // 512 codes per thread
#define CIF  16              // codes in flight (accumulators)
#define NT   (CPT / CIF)     // 32 tiles
#define TPB  128             // threads per block (2 waves)
#define PPB  128             // pixels per block (1 per thread)

// ---------------- K0: init packed argmin keys --------------------------------
__global__ __launch_bounds__(256) void k_init(unsigned long long* __restrict__ packed) {
    packed[blockIdx.x * 256 + threadIdx.x] = ~0ull;
}

// ---------------- K1: normalize codebook, store se_half = 0.5*sum(e_n^2) -----
__global__ __launch_bounds__(256) void k_norm_emb(const float* __restrict__ emb,
                                                  float* __restrict__ e_norm,
                                                  float* __restrict__ se_half) {
    const int wave = threadIdx.x >> 6;        // 4 waves/block, 1 code per wave
    const int lane = threadIdx.x & 63;
    const int n = blockIdx.x * 4 + wave;      // 0..8191
    float v = emb[n * EDIM + lane];
    float ss = v * v;
    #pragma unroll
    for (int off = 32; off; off >>= 1) ss += __shfl_xor(ss, off, 64);
    const float inv = 1.0f / fmaxf(sqrtf(ss), 1e-12f);
    const float en = v * inv;
    e_norm[n * EDIM + lane] = en;
    float s2 = en * en;
    #pragma unroll
    for (int off = 32; off; off >>= 1) s2 += __shfl_xor(s2, off, 64);
    if (lane == 0) se_half[n] = 0.5f * s2;
}

// map float to unsigned with same total order
__device__ __forceinline__ unsigned int order_u32(float f) {
    unsigned int s = __float_as_uint(f);
    return (s & 0x80000000u) ? ~s : (s | 0x80000000u);
}

// ---------------- K2: per-pixel partial argmin over one code group -----------
__global__ __launch_bounds__(TPB) void k_vq_partial(const float* __restrict__ z,
                                                    const float* __restrict__ e_norm,
                                                    const float* __restrict__ se_half,
                                                    unsigned long long* __restrict__ packed) {
    // zs[c4][pixel][4] : channels 4c4..4c4+3 of each pixel, 32 KB.
    // Sweep reads zs4 row c4 at lane-contiguous 16B -> conflict-free b128.
    __shared__ float zs[16 * PPB * 4];

    const int tid = threadIdx.x;
    const int p0  = blockIdx.x * PPB;           // block's first pixel
    const int g   = blockIdx.y;                 // code group 0..15
    const int p   = p0 + tid;
    const int b   = p0 >> 12;                   // whole block in same image b
    const int hw0 = p0 & (HW - 1);

    // ---- one-time: stage block's z slice into LDS (transposed per-channel) --
    const float* zblk = z + b * (EDIM * HW) + hw0;
    #pragma unroll
    for (int c = 0; c < EDIM; ++c) {
        // coalesced global read per channel; scattered-ish LDS write (one-time)
        zs[((c >> 2) * PPB + tid) * 4 + (c & 3)] = zblk[c * HW + tid];
    }
    __syncthreads();

    // ---- per-pixel inverse norm from LDS ------------------------------------
    const float4* zs4 = (const float4*)zs;
    float ss = 0.0f;
    #pragma unroll
    for (int c4 = 0; c4 < 16; ++c4) {
        const float4 v = zs4[c4 * PPB + tid];
        ss = fmaf(v.x, v.x, ss); ss = fmaf(v.y, v.y, ss);
        ss = fmaf(v.z, v.z, ss); ss = fmaf(v.w, v.w, ss);
    }
    const float inv = 1.0f / fmaxf(sqrtf(ss), 1e-12f);

    // ---- sweep this group's codes: 16 in flight -----------------------------
    const float4* __restrict__ e4 = (const float4*)e_norm;
    float best = 3.0e38f;
    int bidx = 0;

    #pragma unroll 1
    for (int t = 0; t < NT; ++t) {
        const int n0 = g * CPT + t * CIF;
        const float* __restrict__ sh = se_half + n0;   // uniform -> s_load

        float acc[CIF];
        #pragma unroll
        for (int j = 0; j < CIF; ++j) acc[j] = 0.0f;

        #pragma unroll
        for (int c4 = 0; c4 < 16; ++c4) {
            const float4 zv = zs4[c4 * PPB + tid];     // 1 ds_read_b128 / 64 FMA
            #pragma unroll
            for (int j = 0; j < CIF; ++j) {
                const float4 ev = e4[(n0 + j) * (EDIM / 4) + c4];  // s_load (uniform)
                acc[j] = fmaf(zv.w, ev.w,
                         fmaf(zv.z, ev.z,
                         fmaf(zv.y, ev.y,
                         fmaf(zv.x, ev.x, acc[j]))));
            }
        }

        #pragma unroll
        for (int j = 0; j < CIF; ++j) {
            const float dist = fmaf(-inv, acc[j], sh[j]);
            // strict < with ascending n keeps smallest index on exact ties
            if (dist < best) { best = dist; bidx = n0 + j; }
        }
    }

    // key = (order(dist) << 32) | idx ; u64 min == (min dist, tie -> min idx).
    const unsigned long long key =
        ((unsigned long long)order_u32(best) << 32) | (unsigned int)bidx;
    atomicMin(&packed[p], key);
}

// ---------------- K3: unpack winner, gather code, write outputs --------------
__global__ __launch_bounds__(256) void k_finalize(const unsigned long long* __restrict__ packed,
                                                  const float* __restrict__ e_norm,
                                                  float* __restrict__ out) {
    const int p = blockIdx.x * 256 + threadIdx.x;
    const int bidx = (int)(packed[p] & 0xFFFFFFFFull);
    out[NPIX * EDIM + p] = (float)bidx;   // indices block, as float values

    const int b  = p >> 12;
    const int hw = p & (HW - 1);
    float* op = out + b * (EDIM * HW) + hw;
    const float* ep = e_norm + bidx * EDIM;
    #pragma unroll
    for (int c = 0; c < EDIM; ++c) op[c * HW] = ep[c];   // coalesced per c
}

extern "C" void kernel_launch(void* const* d_in, const int* in_sizes, int n_in,
                              void* d_out, int out_size, void* d_ws, size_t ws_size,
                              hipStream_t stream) {
    const float* z   = (const float*)d_in[0];   // 2,097,152 fp32
    const float* emb = (const float*)d_in[1];   // 524,288 fp32
    float* out = (float*)d_out;                 // 2,129,920 fp32

    // workspace layout
    float* e_norm  = (float*)d_ws;                                // 524,288 fp32 (2 MB)
    float* se_half = e_norm + NE * EDIM;                          // 8,192 fp32
    unsigned long long* packed = (unsigned long long*)(se_half + NE); // 32,768 u64

    k_init<<<NPIX / 256, 256, 0, stream>>>(packed);
    k_norm_emb<<<NE / 4, 256, 0, stream>>>(emb, e_norm, se_half);
    k_vq_partial<<<dim3(NPIX / PPB, NGRP), TPB, 0, stream>>>(z, e_norm, se_half, packed);
    k_finalize<<<NPIX / 256, 256, 0, stream>>>(packed, e_norm, out);
}

// Round 6
// 501.419 us; speedup vs baseline: 2.2487x; 2.2487x over previous
//
#include <hip/hip_runtime.h>
#include <hip/hip_bf16.h>

// VectorQuantizer: z [8,64,64,64] fp32 (BCHW), embedding [8192,64] fp32.
// Outputs (concat): z_q [8,64,64,64] fp32 (BCHW), indices [32768] as fp32.
//
// R6: move the 17.2 G-MAC distance matrix onto the MFMA pipe (2.38 PF bf16)
// via split precision: zn ~= zh + zl, e ~= eh + el (bf16 hi + bf16 residual).
// dot ~= zh.eh + zh.el + zl.eh  (6x mfma_f32_16x16x32_bf16 per 16x16 K=64 tile;
// missing zl.el + representation error <= ~1.5e-5 on dists in [0,4]).
// Per-pixel top-2 tracked; pixels with top2-top1 < MARGIN (2e-4, 13x bound)
// are re-solved exactly in fp32 (np argmin first-occurrence tie semantics).
// fp32-VALU attempts (R1-R5) plateaued at 654-1127 us vs 218 us issue floor:
// spill (VGPR<=56 allocator cap), LDS throughput (R3), s_load latency (R5).

#define NPIX 32768
#define NE   8192
#define EDIM 64
#define HW   4096
#define NSTAGE 64          // codes per LDS stage
#define LDSPAD 72          // shorts per code row (64 + 8 pad -> 2-way banks, free)
#define MARGIN 2.0e-4f

typedef short bf16x8 __attribute__((ext_vector_type(8)));
typedef float f32x4  __attribute__((ext_vector_type(4)));

__device__ __forceinline__ short f2bf_bits(float x) {
    __hip_bfloat16 h = __float2bfloat16(x);
    short s; __builtin_memcpy(&s, &h, 2); return s;
}
__device__ __forceinline__ float bf_hi_f(float x) {
    return __bfloat162float(__float2bfloat16(x));
}

// ---------------- prep_e: normalize codebook -> e_norm(f32), se_half, eh/el(bf16)
__global__ __launch_bounds__(256) void k_prep_e(const float* __restrict__ emb,
                                                float* __restrict__ e_norm,
                                                float* __restrict__ se_half,
                                                short* __restrict__ eh,
                                                short* __restrict__ el) {
    const int wave = threadIdx.x >> 6;
    const int lane = threadIdx.x & 63;       // = channel
    const int n = blockIdx.x * 4 + wave;
    float v = emb[n * EDIM + lane];
    float ss = v * v;
    #pragma unroll
    for (int off = 32; off; off >>= 1) ss += __shfl_xor(ss, off, 64);
    const float inv = 1.0f / fmaxf(sqrtf(ss), 1e-12f);
    const float en = v * inv;
    e_norm[n * EDIM + lane] = en;
    const float hf = bf_hi_f(en);
    eh[n * EDIM + lane] = f2bf_bits(en);
    el[n * EDIM + lane] = f2bf_bits(en - hf);
    float s2 = en * en;
    #pragma unroll
    for (int off = 32; off; off >>= 1) s2 += __shfl_xor(s2, off, 64);
    if (lane == 0) se_half[n] = 0.5f * s2;
}

// ---------------- prep_z: normalize pixels -> zh/zl bf16 row-major [p][c] ----
__global__ __launch_bounds__(256) void k_prep_z(const float* __restrict__ z,
                                                short* __restrict__ zh,
                                                short* __restrict__ zl) {
    const int p = blockIdx.x * 256 + threadIdx.x;
    const int b = p >> 12, hw = p & (HW - 1);
    const float* zp = z + b * (EDIM * HW) + hw;
    float ss = 0.0f;
    for (int c = 0; c < EDIM; ++c) { const float v = zp[c * HW]; ss = fmaf(v, v, ss); }
    const float inv = 1.0f / fmaxf(sqrtf(ss), 1e-12f);
    for (int c4 = 0; c4 < 16; ++c4) {
        short4 h4, l4;
        float zn, hf;
        zn = zp[(c4*4+0) * HW] * inv; hf = bf_hi_f(zn); h4.x = f2bf_bits(zn); l4.x = f2bf_bits(zn - hf);
        zn = zp[(c4*4+1) * HW] * inv; hf = bf_hi_f(zn); h4.y = f2bf_bits(zn); l4.y = f2bf_bits(zn - hf);
        zn = zp[(c4*4+2) * HW] * inv; hf = bf_hi_f(zn); h4.z = f2bf_bits(zn); l4.z = f2bf_bits(zn - hf);
        zn = zp[(c4*4+3) * HW] * inv; hf = bf_hi_f(zn); h4.w = f2bf_bits(zn); l4.w = f2bf_bits(zn - hf);
        *(short4*)(zh + p * EDIM + c4 * 4) = h4;
        *(short4*)(zl + p * EDIM + c4 * 4) = l4;
    }
}

// ---------------- k_mfma: all 32768x8192 dists, per-pixel top-2 + flag -------
// Block: 4 waves x 16 pixels = 64 pixels; loops all 8192 codes via 64-code LDS
// stages. Layouts (HW-verified, guide §3): A[m=lane&15][k=quad*8+j],
// B[k=quad*8+j][n=lane&15], C/D row=(lane>>4)*4+reg, col=lane&15.
__global__ __launch_bounds__(256, 1) void k_mfma(const short* __restrict__ zh,
                                                 const short* __restrict__ zl,
                                                 const short* __restrict__ eh,
                                                 const short* __restrict__ el,
                                                 const float* __restrict__ se_half,
                                                 unsigned* __restrict__ idx_arr,
                                                 unsigned* __restrict__ list,
                                                 unsigned* __restrict__ counter) {
    __shared__ short esh[NSTAGE * LDSPAD];
    __shared__ short esl[NSTAGE * LDSPAD];
    __shared__ float ses[NSTAGE];

    const int tid  = threadIdx.x;
    const int wave = tid >> 6, lane = tid & 63;
    const int quad = lane >> 4, col = lane & 15;
    const int p0   = blockIdx.x * 64 + wave * 16;   // wave's 16 pixels

    // A fragments (per-wave resident, reused for all 8192 codes)
    const int arow = (p0 + col) * EDIM;
    const bf16x8 ah0 = *(const bf16x8*)(zh + arow +  0 + quad * 8);
    const bf16x8 ah1 = *(const bf16x8*)(zh + arow + 32 + quad * 8);
    const bf16x8 al0 = *(const bf16x8*)(zl + arow +  0 + quad * 8);
    const bf16x8 al1 = *(const bf16x8*)(zl + arow + 32 + quad * 8);

    float b1[4], b2[4]; int i1[4];
    #pragma unroll
    for (int r = 0; r < 4; ++r) { b1[r] = 3.0e38f; b2[r] = 3.0e38f; i1[r] = 0; }

    const int s_code = tid >> 2;        // 0..63
    const int s_ch   = (tid & 3) * 16;  // 16 shorts (32 B) per thread

    for (int nb = 0; nb < NE / NSTAGE; ++nb) {
        { // stage 64 codes (hi+lo+se) into LDS
            const short* sh = eh + (nb * NSTAGE + s_code) * EDIM + s_ch;
            const short* sl = el + (nb * NSTAGE + s_code) * EDIM + s_ch;
            short* dh = esh + s_code * LDSPAD + s_ch;
            short* dl = esl + s_code * LDSPAD + s_ch;
            ((int4*)dh)[0] = ((const int4*)sh)[0];
            ((int4*)dh)[1] = ((const int4*)sh)[1];
            ((int4*)dl)[0] = ((const int4*)sl)[0];
            ((int4*)dl)[1] = ((const int4*)sl)[1];
            if (tid < NSTAGE) ses[tid] = se_half[nb * NSTAGE + tid];
        }
        __syncthreads();
        #pragma unroll
        for (int sub = 0; sub < NSTAGE / 16; ++sub) {
            const int nloc = sub * 16 + col;
            const short* bh = esh + nloc * LDSPAD + quad * 8;
            const short* bl = esl + nloc * LDSPAD + quad * 8;
            const bf16x8 bh0 = *(const bf16x8*)(bh);
            const bf16x8 bh1 = *(const bf16x8*)(bh + 32);
            const bf16x8 bl0 = *(const bf16x8*)(bl);
            const bf16x8 bl1 = *(const bf16x8*)(bl + 32);
            const float sse = ses[nloc];
            f32x4 acc  = {0.f, 0.f, 0.f, 0.f};   // hi*hi
            f32x4 acc2 = {0.f, 0.f, 0.f, 0.f};   // cross terms (2nd chain for ILP)
            acc  = __builtin_amdgcn_mfma_f32_16x16x32_bf16(ah0, bh0, acc,  0, 0, 0);
            acc  = __builtin_amdgcn_mfma_f32_16x16x32_bf16(ah1, bh1, acc,  0, 0, 0);
            acc2 = __builtin_amdgcn_mfma_f32_16x16x32_bf16(ah0, bl0, acc2, 0, 0, 0);
            acc2 = __builtin_amdgcn_mfma_f32_16x16x32_bf16(ah1, bl1, acc2, 0, 0, 0);
            acc2 = __builtin_amdgcn_mfma_f32_16x16x32_bf16(al0, bh0, acc2, 0, 0, 0);
            acc2 = __builtin_amdgcn_mfma_f32_16x16x32_bf16(al1, bh1, acc2, 0, 0, 0);
            const int nglob = nb * NSTAGE + nloc;
            #pragma unroll
            for (int r = 0; r < 4; ++r) {
                const float dist = sse - acc[r] - acc2[r];
                b2[r] = fminf(b2[r], fmaxf(b1[r], dist));   // new 2nd-best
                const bool t = dist < b1[r];                // strict <, n ascending
                b1[r] = fminf(b1[r], dist);
                i1[r] = t ? nglob : i1[r];
            }
        }
        __syncthreads();
    }

    // merge top-2 across the 16 col-lanes (xor 1,2,4,8 stays inside quad group)
    #pragma unroll
    for (int m = 1; m <= 8; m <<= 1) {
        #pragma unroll
        for (int r = 0; r < 4; ++r) {
            const float ob1 = __shfl_xor(b1[r], m, 64);
            const int   oi1 = __shfl_xor(i1[r], m, 64);
            const float ob2 = __shfl_xor(b2[r], m, 64);
            const bool take = (ob1 < b1[r]) || (ob1 == b1[r] && oi1 < i1[r]);
            b2[r] = fminf(fminf(b2[r], ob2), fmaxf(b1[r], ob1));
            b1[r] = take ? ob1 : b1[r];
            i1[r] = take ? oi1 : i1[r];
        }
    }
    if (col == 0) {
        #pragma unroll
        for (int r = 0; r < 4; ++r) {
            const int p = p0 + quad * 4 + r;    // C/D row = quad*4 + r
            idx_arr[p] = (unsigned)i1[r];
            if (b2[r] - b1[r] < MARGIN) {       // near-tie: exact fp32 recheck
                const unsigned pos = atomicAdd(counter, 1u);
                if (pos < NPIX) list[pos] = p;
            }
        }
    }
}

// ---------------- recheck: exact fp32 argmin for flagged pixels --------------
__global__ __launch_bounds__(256) void k_recheck(const float* __restrict__ z,
                                                 const float* __restrict__ e_norm,
                                                 const float* __restrict__ se_half,
                                                 const unsigned* __restrict__ list,
                                                 const unsigned* __restrict__ counter,
                                                 unsigned* __restrict__ idx_arr) {
    __shared__ float zsh[4][EDIM];
    const int wave = threadIdx.x >> 6, lane = threadIdx.x & 63;
    int cnt = (int)*counter; if (cnt > NPIX) cnt = NPIX;

    for (int base = blockIdx.x * 4; base < cnt; base += gridDim.x * 4) {
        const int it = base + wave;
        const bool active = it < cnt;
        int p = 0;
        if (active) {
            p = (int)list[it];
            const int b = p >> 12, hw = p & (HW - 1);
            const float v = z[(b * EDIM + lane) * HW + hw];   // lane = channel
            float ss = v * v;
            #pragma unroll
            for (int off = 32; off; off >>= 1) ss += __shfl_xor(ss, off, 64);
            const float inv = 1.0f / fmaxf(sqrtf(ss), 1e-12f);
            zsh[wave][lane] = v * inv;
        }
        __syncthreads();   // uniform trip count across block's waves
        if (active) {
            const float4* zn4 = (const float4*)zsh[wave];
            const float4* e4  = (const float4*)e_norm;
            float best = 3.0e38f; int bidx = 0;
            for (int j = 0; j < NE / 64; j += 2) {         // lane's codes: j*64+lane
                const int n0 = j * 64 + lane, n1 = n0 + 64;
                float a0 = 0.f, a1 = 0.f;
                #pragma unroll
                for (int c4 = 0; c4 < 16; ++c4) {
                    const float4 zv = zn4[c4];             // LDS broadcast
                    const float4 e0 = e4[n0 * 16 + c4];
                    const float4 e1 = e4[n1 * 16 + c4];
                    a0 = fmaf(zv.w, e0.w, fmaf(zv.z, e0.z, fmaf(zv.y, e0.y, fmaf(zv.x, e0.x, a0))));
                    a1 = fmaf(zv.w, e1.w, fmaf(zv.z, e1.z, fmaf(zv.y, e1.y, fmaf(zv.x, e1.x, a1))));
                }
                const float d0 = se_half[n0] - a0;
                const float d1 = se_half[n1] - a1;
                if (d0 < best) { best = d0; bidx = n0; }   // strict <, ascending
                if (d1 < best) { best = d1; bidx = n1; }
            }
            #pragma unroll
            for (int m = 1; m <= 32; m <<= 1) {            // global first-min
                const float ob = __shfl_xor(best, m, 64);
                const int   oi = __shfl_xor(bidx, m, 64);
                if (ob < best || (ob == best && oi < bidx)) { best = ob; bidx = oi; }
            }
            if (lane == 0) idx_arr[p] = (unsigned)bidx;
        }
        __syncthreads();   // zsh reused next iteration
    }
}

// ---------------- finalize: write indices + gather z_q -----------------------
__global__ __launch_bounds__(256) void k_finalize(const unsigned* __restrict__ idx_arr,
                                                  const float* __restrict__ e_norm,
                                                  float* __restrict__ out) {
    const int p = blockIdx.x * 256 + threadIdx.x;
    const int bidx = (int)idx_arr[p];
    out[NPIX * EDIM + p] = (float)bidx;
    const int b = p >> 12, hw = p & (HW - 1);
    float* op = out + b * (EDIM * HW) + hw;
    const float* ep = e_norm + bidx * EDIM;
    #pragma unroll
    for (int c = 0; c < EDIM; ++c) op[c * HW] = ep[c];   // coalesced per c
}

extern "C" void kernel_launch(void* const* d_in, const int* in_sizes, int n_in,
                              void* d_out, int out_size, void* d_ws, size_t ws_size,
                              hipStream_t stream) {
    const float* z   = (const float*)d_in[0];
    const float* emb = (const float*)d_in[1];
    float* out = (float*)d_out;

    // workspace layout (~12.3 MB)
    float* e_norm  = (float*)d_ws;                       // 2 MB
    float* se_half = e_norm + NE * EDIM;                 // 32 KB
    short* eh = (short*)(se_half + NE);                  // 1 MB
    short* el = eh + NE * EDIM;                          // 1 MB
    short* zh = el + NE * EDIM;                          // 4 MB
    short* zl = zh + NPIX * EDIM;                        // 4 MB
    unsigned* idx_arr = (unsigned*)(zl + NPIX * EDIM);   // 128 KB
    unsigned* list    = idx_arr + NPIX;                  // 128 KB
    unsigned* counter = list + NPIX;                     // 4 B

    hipMemsetAsync(counter, 0, sizeof(unsigned), stream);
    k_prep_e<<<NE / 4, 256, 0, stream>>>(emb, e_norm, se_half, eh, el);
    k_prep_z<<<NPIX / 256, 256, 0, stream>>>(z, zh, zl);
    k_mfma<<<NPIX / 64, 256, 0, stream>>>(zh, zl, eh, el, se_half,
                                          idx_arr, list, counter);
    k_recheck<<<128, 256, 0, stream>>>(z, e_norm, se_half, list, counter, idx_arr);
    k_finalize<<<NPIX / 256, 256, 0, stream>>>(idx_arr, e_norm, out);
}

// Round 7
// 358.647 us; speedup vs baseline: 3.1438x; 1.3981x over previous
//
#include <hip/hip_runtime.h>
#include <hip/hip_bf16.h>

// VectorQuantizer: z [8,64,64,64] fp32 (BCHW), embedding [8192,64] fp32.
// Outputs (concat): z_q [8,64,64,64] fp32 (BCHW), indices [32768] as fp32.
//
// R7: R6's bf16-split MFMA distance matrix kept verbatim; the recheck (R6's
// top dispatch: 257 us at VALUBusy 1.3%, latency-bound serial scan over ~512
// waves) is re-parallelized: item = (flagged pixel x 16 code-chunks), 4096
// waves grid-striding, packed u64 atomicMin (exact np tie semantics).
// prep_z now stores zn fp32 (replaces zh/zl globals; k_mfma splits to bf16
// hi/lo in registers once per wave; recheck s_loads zn at uniform address).

#define NPIX 32768
#define NE   8192
#define EDIM 64
#define HW   4096
#define NSTAGE 64          // codes per LDS stage
#define LDSPAD 72          // shorts per code row (64 + 8 pad -> 2-way banks, free)
#define MARGIN 2.0e-4f

typedef short bf16x8 __attribute__((ext_vector_type(8)));
typedef float f32x4  __attribute__((ext_vector_type(4)));

__device__ __forceinline__ short f2bf_bits(float x) {
    __hip_bfloat16 h = __float2bfloat16(x);
    short s; __builtin_memcpy(&s, &h, 2); return s;
}
__device__ __forceinline__ float bf_hi_f(float x) {
    return __bfloat162float(__float2bfloat16(x));
}
// map float to unsigned with same total order
__device__ __forceinline__ unsigned int order_u32(float f) {
    unsigned int s = __float_as_uint(f);
    return (s & 0x80000000u) ? ~s : (s | 0x80000000u);
}

// ---------------- prep_e: normalize codebook -> e_norm(f32), se_half, eh/el(bf16)
__global__ __launch_bounds__(256) void k_prep_e(const float* __restrict__ emb,
                                                float* __restrict__ e_norm,
                                                float* __restrict__ se_half,
                                                short* __restrict__ eh,
                                                short* __restrict__ el) {
    const int wave = threadIdx.x >> 6;
    const int lane = threadIdx.x & 63;       // = channel
    const int n = blockIdx.x * 4 + wave;
    float v = emb[n * EDIM + lane];
    float ss = v * v;
    #pragma unroll
    for (int off = 32; off; off >>= 1) ss += __shfl_xor(ss, off, 64);
    const float inv = 1.0f / fmaxf(sqrtf(ss), 1e-12f);
    const float en = v * inv;
    e_norm[n * EDIM + lane] = en;
    const float hf = bf_hi_f(en);
    eh[n * EDIM + lane] = f2bf_bits(en);
    el[n * EDIM + lane] = f2bf_bits(en - hf);
    float s2 = en * en;
    #pragma unroll
    for (int off = 32; off; off >>= 1) s2 += __shfl_xor(s2, off, 64);
    if (lane == 0) se_half[n] = 0.5f * s2;
}

// ---------------- prep_z: normalize pixels -> zn fp32 row-major [p][c] -------
__global__ __launch_bounds__(256) void k_prep_z(const float* __restrict__ z,
                                                float* __restrict__ zn) {
    const int p = blockIdx.x * 256 + threadIdx.x;
    const int b = p >> 12, hw = p & (HW - 1);
    const float* zp = z + b * (EDIM * HW) + hw;
    float ss = 0.0f;
    for (int c = 0; c < EDIM; ++c) { const float v = zp[c * HW]; ss = fmaf(v, v, ss); }
    const float inv = 1.0f / fmaxf(sqrtf(ss), 1e-12f);
    for (int c4 = 0; c4 < 16; ++c4) {
        float4 o;
        o.x = zp[(c4 * 4 + 0) * HW] * inv;
        o.y = zp[(c4 * 4 + 1) * HW] * inv;
        o.z = zp[(c4 * 4 + 2) * HW] * inv;
        o.w = zp[(c4 * 4 + 3) * HW] * inv;
        *(float4*)(zn + p * EDIM + c4 * 4) = o;
    }
}

// ---------------- k_mfma: all 32768x8192 dists, per-pixel top-2 + flag -------
// Block: 4 waves x 16 pixels = 64 pixels; loops all 8192 codes via 64-code LDS
// stages. Layouts (HW-verified, guide §3): A[m=lane&15][k=quad*8+j],
// B[k=quad*8+j][n=lane&15], C/D row=(lane>>4)*4+reg, col=lane&15.
__global__ __launch_bounds__(256, 1) void k_mfma(const float* __restrict__ zn,
                                                 const short* __restrict__ eh,
                                                 const short* __restrict__ el,
                                                 const float* __restrict__ se_half,
                                                 unsigned* __restrict__ idx_arr,
                                                 unsigned* __restrict__ list,
                                                 unsigned* __restrict__ counter,
                                                 unsigned long long* __restrict__ packed) {
    __shared__ short esh[NSTAGE * LDSPAD];
    __shared__ short esl[NSTAGE * LDSPAD];
    __shared__ float ses[NSTAGE];

    const int tid  = threadIdx.x;
    const int wave = tid >> 6, lane = tid & 63;
    const int quad = lane >> 4, col = lane & 15;
    const int p0   = blockIdx.x * 64 + wave * 16;   // wave's 16 pixels

    // A fragments: load zn fp32 once, split to bf16 hi + residual lo in regs.
    const float* zr = zn + (p0 + col) * EDIM;
    bf16x8 ah0, ah1, al0, al1;
    {
        const float4 v0 = *(const float4*)(zr + quad * 8);
        const float4 v1 = *(const float4*)(zr + quad * 8 + 4);
        const float4 v2 = *(const float4*)(zr + 32 + quad * 8);
        const float4 v3 = *(const float4*)(zr + 32 + quad * 8 + 4);
        const float f0[8] = {v0.x, v0.y, v0.z, v0.w, v1.x, v1.y, v1.z, v1.w};
        const float f1[8] = {v2.x, v2.y, v2.z, v2.w, v3.x, v3.y, v3.z, v3.w};
        #pragma unroll
        for (int i = 0; i < 8; ++i) {
            ah0[i] = f2bf_bits(f0[i]); al0[i] = f2bf_bits(f0[i] - bf_hi_f(f0[i]));
            ah1[i] = f2bf_bits(f1[i]); al1[i] = f2bf_bits(f1[i] - bf_hi_f(f1[i]));
        }
    }

    float b1[4], b2[4]; int i1[4];
    #pragma unroll
    for (int r = 0; r < 4; ++r) { b1[r] = 3.0e38f; b2[r] = 3.0e38f; i1[r] = 0; }

    const int s_code = tid >> 2;        // 0..63
    const int s_ch   = (tid & 3) * 16;  // 16 shorts (32 B) per thread

    for (int nb = 0; nb < NE / NSTAGE; ++nb) {
        { // stage 64 codes (hi+lo+se) into LDS
            const short* sh = eh + (nb * NSTAGE + s_code) * EDIM + s_ch;
            const short* sl = el + (nb * NSTAGE + s_code) * EDIM + s_ch;
            short* dh = esh + s_code * LDSPAD + s_ch;
            short* dl = esl + s_code * LDSPAD + s_ch;
            ((int4*)dh)[0] = ((const int4*)sh)[0];
            ((int4*)dh)[1] = ((const int4*)sh)[1];
            ((int4*)dl)[0] = ((const int4*)sl)[0];
            ((int4*)dl)[1] = ((const int4*)sl)[1];
            if (tid < NSTAGE) ses[tid] = se_half[nb * NSTAGE + tid];
        }
        __syncthreads();
        #pragma unroll
        for (int sub = 0; sub < NSTAGE / 16; ++sub) {
            const int nloc = sub * 16 + col;
            const short* bh = esh + nloc * LDSPAD + quad * 8;
            const short* bl = esl + nloc * LDSPAD + quad * 8;
            const bf16x8 bh0 = *(const bf16x8*)(bh);
            const bf16x8 bh1 = *(const bf16x8*)(bh + 32);
            const bf16x8 bl0 = *(const bf16x8*)(bl);
            const bf16x8 bl1 = *(const bf16x8*)(bl + 32);
            const float sse = ses[nloc];
            f32x4 acc  = {0.f, 0.f, 0.f, 0.f};   // hi*hi
            f32x4 acc2 = {0.f, 0.f, 0.f, 0.f};   // cross terms (2nd chain for ILP)
            acc  = __builtin_amdgcn_mfma_f32_16x16x32_bf16(ah0, bh0, acc,  0, 0, 0);
            acc  = __builtin_amdgcn_mfma_f32_16x16x32_bf16(ah1, bh1, acc,  0, 0, 0);
            acc2 = __builtin_amdgcn_mfma_f32_16x16x32_bf16(ah0, bl0, acc2, 0, 0, 0);
            acc2 = __builtin_amdgcn_mfma_f32_16x16x32_bf16(ah1, bl1, acc2, 0, 0, 0);
            acc2 = __builtin_amdgcn_mfma_f32_16x16x32_bf16(al0, bh0, acc2, 0, 0, 0);
            acc2 = __builtin_amdgcn_mfma_f32_16x16x32_bf16(al1, bh1, acc2, 0, 0, 0);
            const int nglob = nb * NSTAGE + nloc;
            #pragma unroll
            for (int r = 0; r < 4; ++r) {
                const float dist = sse - acc[r] - acc2[r];
                b2[r] = fminf(b2[r], fmaxf(b1[r], dist));   // new 2nd-best
                const bool t = dist < b1[r];                // strict <, n ascending
                b1[r] = fminf(b1[r], dist);
                i1[r] = t ? nglob : i1[r];
            }
        }
        __syncthreads();
    }

    // merge top-2 across the 16 col-lanes (xor 1,2,4,8 stays inside quad group)
    #pragma unroll
    for (int m = 1; m <= 8; m <<= 1) {
        #pragma unroll
        for (int r = 0; r < 4; ++r) {
            const float ob1 = __shfl_xor(b1[r], m, 64);
            const int   oi1 = __shfl_xor(i1[r], m, 64);
            const float ob2 = __shfl_xor(b2[r], m, 64);
            const bool take = (ob1 < b1[r]) || (ob1 == b1[r] && oi1 < i1[r]);
            b2[r] = fminf(fminf(b2[r], ob2), fmaxf(b1[r], ob1));
            b1[r] = take ? ob1 : b1[r];
            i1[r] = take ? oi1 : i1[r];
        }
    }
    if (col == 0) {
        #pragma unroll
        for (int r = 0; r < 4; ++r) {
            const int p = p0 + quad * 4 + r;    // C/D row = quad*4 + r
            idx_arr[p] = (unsigned)i1[r];
            if (b2[r] - b1[r] < MARGIN) {       // near-tie: exact fp32 recheck
                packed[p] = ~0ull;              // init argmin key for recheck
                const unsigned pos = atomicAdd(counter, 1u);
                if (pos < NPIX) list[pos] = p;
            }
        }
    }
}

// ---------------- recheck: exact fp32 argmin for flagged pixels --------------
// item = (flagged pixel, 512-code chunk); 4096 waves grid-stride. zn read at
// wave-uniform address -> s_load (SGPR-resident pixel vector).
__global__ __launch_bounds__(256) void k_recheck(const float* __restrict__ zn,
                                                 const float* __restrict__ e_norm,
                                                 const float* __restrict__ se_half,
                                                 const unsigned* __restrict__ list,
                                                 const unsigned* __restrict__ counter,
                                                 unsigned long long* __restrict__ packed) {
    const int lane  = threadIdx.x & 63;
    const int wglob = (blockIdx.x * 256 + threadIdx.x) >> 6;
    const int nwav  = (gridDim.x * 256) >> 6;
    int cnt = (int)*counter; if (cnt > NPIX) cnt = NPIX;
    const int nitems = cnt * 16;

    for (int item = wglob; item < nitems; item += nwav) {
        const int p     = (int)list[item >> 4];
        const int chunk = item & 15;
        const float4* zp4 = (const float4*)(zn + p * EDIM);   // uniform -> s_load
        const float4* e4  = (const float4*)e_norm;
        float best = 3.0e38f; int bidx = 0;
        #pragma unroll 1
        for (int j = 0; j < 8; j += 2) {                      // lane codes, ILP 2
            const int n0 = chunk * 512 + j * 64 + lane;
            const int n1 = n0 + 64;
            float a0 = 0.f, a1 = 0.f;
            #pragma unroll
            for (int c4 = 0; c4 < 16; ++c4) {
                const float4 zv = zp4[c4];
                const float4 e0 = e4[n0 * 16 + c4];
                const float4 e1 = e4[n1 * 16 + c4];
                a0 = fmaf(zv.w, e0.w, fmaf(zv.z, e0.z, fmaf(zv.y, e0.y, fmaf(zv.x, e0.x, a0))));
                a1 = fmaf(zv.w, e1.w, fmaf(zv.z, e1.z, fmaf(zv.y, e1.y, fmaf(zv.x, e1.x, a1))));
            }
            const float d0 = se_half[n0] - a0;
            const float d1 = se_half[n1] - a1;
            if (d0 < best) { best = d0; bidx = n0; }          // strict <, ascending
            if (d1 < best) { best = d1; bidx = n1; }
        }
        #pragma unroll
        for (int m = 1; m <= 32; m <<= 1) {                   // wave first-min
            const float ob = __shfl_xor(best, m, 64);
            const int   oi = __shfl_xor(bidx, m, 64);
            if (ob < best || (ob == best && oi < bidx)) { best = ob; bidx = oi; }
        }
        if (lane == 0) {
            const unsigned long long key =
                ((unsigned long long)order_u32(best) << 32) | (unsigned)bidx;
            atomicMin(&packed[p], key);
        }
    }
}

// ---------------- apply: recheck winners -> idx_arr --------------------------
__global__ __launch_bounds__(256) void k_apply(const unsigned* __restrict__ list,
                                               const unsigned* __restrict__ counter,
                                               const unsigned long long* __restrict__ packed,
                                               unsigned* __restrict__ idx_arr) {
    int cnt = (int)*counter; if (cnt > NPIX) cnt = NPIX;
    for (int i = blockIdx.x * 256 + threadIdx.x; i < cnt; i += gridDim.x * 256) {
        const int p = (int)list[i];
        idx_arr[p] = (unsigned)(packed[p] & 0xFFFFFFFFull);
    }
}

// ---------------- finalize: write indices + gather z_q -----------------------
__global__ __launch_bounds__(256) void k_finalize(const unsigned* __restrict__ idx_arr,
                                                  const float* __restrict__ e_norm,
                                                  float* __restrict__ out) {
    const int p = blockIdx.x * 256 + threadIdx.x;
    const int bidx = (int)idx_arr[p];
    out[NPIX * EDIM + p] = (float)bidx;
    const int b = p >> 12, hw = p & (HW - 1);
    float* op = out + b * (EDIM * HW) + hw;
    const float* ep = e_norm + bidx * EDIM;
    #pragma unroll
    for (int c = 0; c < EDIM; ++c) op[c * HW] = ep[c];   // coalesced per c
}

extern "C" void kernel_launch(void* const* d_in, const int* in_sizes, int n_in,
                              void* d_out, int out_size, void* d_ws, size_t ws_size,
                              hipStream_t stream) {
    const float* z   = (const float*)d_in[0];
    const float* emb = (const float*)d_in[1];
    float* out = (float*)d_out;

    // workspace layout (~12.6 MB)
    float* e_norm  = (float*)d_ws;                       // 2 MB
    float* se_half = e_norm + NE * EDIM;                 // 32 KB
    short* eh = (short*)(se_half + NE);                  // 1 MB
    short* el = eh + NE * EDIM;                          // 1 MB
    float* zn = (float*)(el + NE * EDIM);                // 8 MB
    unsigned* idx_arr = (unsigned*)(zn + NPIX * EDIM);   // 128 KB
    unsigned* list    = idx_arr + NPIX;                  // 128 KB
    unsigned* counter = list + NPIX;                     // 4 B (+pad)
    unsigned long long* packed = (unsigned long long*)(counter + 64); // 256 KB

    hipMemsetAsync(counter, 0, sizeof(unsigned), stream);
    k_prep_e<<<NE / 4, 256, 0, stream>>>(emb, e_norm, se_half, eh, el);
    k_prep_z<<<NPIX / 256, 256, 0, stream>>>(z, zn);
    k_mfma<<<NPIX / 64, 256, 0, stream>>>(zn, eh, el, se_half,
                                          idx_arr, list, counter, packed);
    k_recheck<<<1024, 256, 0, stream>>>(zn, e_norm, se_half, list, counter, packed);
    k_apply<<<32, 256, 0, stream>>>(list, counter, packed, idx_arr);
    k_finalize<<<NPIX / 256, 256, 0, stream>>>(idx_arr, e_norm, out);
}